// Round 1
// baseline (7841.178 us; speedup 1.0000x reference)
//
#include <hip/hip_runtime.h>
#include <math.h>

#define B_ 64
#define T_ 1024
#define I_ 128
#define H_ 512

// Prep: transpose weights for coalesced streaming.
// wt_hh[k][j] = W_hh[j][k]  (512x512), wt_ih[i][h] = W_ih[h][i] (128x512)
__global__ void transpose_prep(const float* __restrict__ wih,
                               const float* __restrict__ whh,
                               float* __restrict__ wt_ih,
                               float* __restrict__ wt_hh) {
    int e = blockIdx.x * 256 + threadIdx.x;
    if (e < H_ * H_) {
        int k = e >> 9;          // row of wt_hh
        int j = e & (H_ - 1);    // col of wt_hh
        wt_hh[e] = whh[j * H_ + k];
    }
    if (e < I_ * H_) {
        int i = e >> 9;
        int h = e & (H_ - 1);
        wt_ih[e] = wih[h * I_ + i];
    }
}

// One workgroup per batch element; 1024 threads = 8 k-chunks x 128 col-groups.
// Thread (c,g) accumulates outputs [4g,4g+4) over k-slice c.
__global__ __launch_bounds__(1024) void rnn_fused(
    const float* __restrict__ x,     // [B,T,I]
    const float* __restrict__ b_ih,  // [H]
    const float* __restrict__ b_hh,  // [H]
    const float* __restrict__ fc_w,  // [H]
    const float* __restrict__ fc_b,  // [1]
    const float* __restrict__ wt_ih, // [I][H]
    const float* __restrict__ wt_hh, // [H][H] (transposed)
    float* __restrict__ out)         // [B]
{
    __shared__ float x_lds[I_];
    __shared__ float h_lds[H_];
    __shared__ float part[8][H_];   // 16 KB partial sums
    __shared__ float wsum[16];

    const int tid = threadIdx.x;
    const int b   = blockIdx.x;
    const int c   = tid >> 7;       // 0..7  (constant within a wave)
    const int g   = tid & 127;      // 0..127 (lane-consecutive)
    const int j0  = g << 2;

    const float4* wtih4 = (const float4*)wt_ih;
    const float4* wthh4 = (const float4*)wt_hh;
    const float*  xb    = x + (size_t)b * T_ * I_;

    if (tid < H_) h_lds[tid] = 0.0f;
    if (tid < I_) x_lds[tid] = xb[tid];
    const float biasr = (tid < H_) ? (b_ih[tid] + b_hh[tid]) : 0.0f;
    __syncthreads();

    for (int t = 0; t < T_; ++t) {
        // prefetch next x row into registers (lands in LDS after barrier 1)
        float xpre = 0.0f;
        if (tid < I_ && t + 1 < T_) xpre = xb[(size_t)(t + 1) * I_ + tid];

        float a0 = 0.f, a1 = 0.f, a2 = 0.f, a3 = 0.f;

        // input projection slice: i in [c*16, c*16+16)
        const int ibase = c * 16;
        #pragma unroll
        for (int ii = 0; ii < 16; ++ii) {
            const int i = ibase + ii;
            const float xv = x_lds[i];               // LDS broadcast
            const float4 w = wtih4[i * 128 + g];     // coalesced 16B/lane
            a0 += xv * w.x; a1 += xv * w.y; a2 += xv * w.z; a3 += xv * w.w;
        }
        // recurrent slice: k in [c*64, c*64+64)
        const int kbase = c * 64;
        #pragma unroll 8
        for (int kk = 0; kk < 64; ++kk) {
            const int k = kbase + kk;
            const float hv = h_lds[k];               // LDS broadcast
            const float4 w = wthh4[k * 128 + g];     // coalesced 16B/lane
            a0 += hv * w.x; a1 += hv * w.y; a2 += hv * w.z; a3 += hv * w.w;
        }

        part[c][j0 + 0] = a0;
        part[c][j0 + 1] = a1;
        part[c][j0 + 2] = a2;
        part[c][j0 + 3] = a3;
        __syncthreads();                             // barrier 1

        if (tid < H_) {
            float pre = biasr;
            #pragma unroll
            for (int cc = 0; cc < 8; ++cc) pre += part[cc][tid];
            h_lds[tid] = tanhf(pre);
        }
        if (tid < I_) x_lds[tid] = xpre;
        __syncthreads();                             // barrier 2
    }

    // final head: out[b] = dot(h, fc_w) + fc_b
    float p = (tid < H_) ? h_lds[tid] * fc_w[tid] : 0.0f;
    #pragma unroll
    for (int off = 32; off >= 1; off >>= 1) p += __shfl_down(p, off, 64);
    if ((tid & 63) == 0) wsum[tid >> 6] = p;
    __syncthreads();
    if (tid == 0) {
        float s = fc_b[0];
        #pragma unroll
        for (int w = 0; w < 16; ++w) s += wsum[w];
        out[b] = s;
    }
}

extern "C" void kernel_launch(void* const* d_in, const int* in_sizes, int n_in,
                              void* d_out, int out_size, void* d_ws, size_t ws_size,
                              hipStream_t stream) {
    const float* x   = (const float*)d_in[0];
    const float* wih = (const float*)d_in[1];
    const float* whh = (const float*)d_in[2];
    const float* bih = (const float*)d_in[3];
    const float* bhh = (const float*)d_in[4];
    const float* fcw = (const float*)d_in[5];
    const float* fcb = (const float*)d_in[6];
    float* out = (float*)d_out;

    float* wt_hh = (float*)d_ws;                 // 512*512 floats
    float* wt_ih = wt_hh + H_ * H_;              // 128*512 floats

    hipLaunchKernelGGL(transpose_prep,
                       dim3((H_ * H_ + 255) / 256), dim3(256), 0, stream,
                       wih, whh, wt_ih, wt_hh);
    hipLaunchKernelGGL(rnn_fused,
                       dim3(B_), dim3(1024), 0, stream,
                       x, bih, bhh, fcw, fcb, wt_ih, wt_hh, out);
}

// Round 2
// 1605.325 us; speedup vs baseline: 4.8845x; 4.8845x over previous
//
#include <hip/hip_runtime.h>
#include <math.h>

#define B_ 64
#define T_ 1024
#define I_ 128
#define H_ 512

typedef _Float16 h2_t __attribute__((ext_vector_type(2)));
union U32H2 { unsigned u; h2_t h; };

__device__ __forceinline__ float fdot2u(unsigned a, unsigned b, float c) {
    U32H2 ua, ub; ua.u = a; ub.u = b;
    return __builtin_amdgcn_fdot2(ua.h, ub.h, c, false);
}

__device__ __forceinline__ unsigned packh2(float x, float y) {
    U32H2 r; r.h.x = (_Float16)x; r.h.y = (_Float16)y; return r.u;
}

// ---------------- prep: pack fp16 weight layouts into workspace ----------------
// wpack[tid*192 + j*48 + kk2] = half2(Whh[4g+j][c*128+2kk2], Whh[4g+j][c*128+2kk2+1])
//   where tid=(c<<7)|g  (register-resident part: k in [c*128, c*128+96))
// wldsg[((c*16+m)<<9)+col]   = half2(Whh[col][c*128+96+2m], ...+1)   (LDS part)
// wih2[(i2<<9)+h]            = half2(Wih[h][2i2], Wih[h][2i2+1])
// biasv[h] = b_ih[h] + b_hh[h]
__global__ void prep(const float* __restrict__ wih, const float* __restrict__ whh,
                     const float* __restrict__ bih, const float* __restrict__ bhh,
                     unsigned* __restrict__ wpack, unsigned* __restrict__ wldsg,
                     unsigned* __restrict__ wih2, float* __restrict__ biasv) {
    int e = blockIdx.x * 256 + threadIdx.x;
    if (e < 512 * 192) {
        int tid = e / 192, r = e % 192;
        int j = r / 48, kk2 = r % 48;
        int c = tid >> 7, g = tid & 127;
        int row = (g << 2) + j;
        int col = (c << 7) + (kk2 << 1);
        wpack[e] = packh2(whh[row * H_ + col], whh[row * H_ + col + 1]);
    }
    if (e < 4 * 16 * 512) {
        int c = e >> 13, m = (e >> 9) & 15, col = e & 511;
        int k = (c << 7) + 96 + (m << 1);
        wldsg[e] = packh2(whh[col * H_ + k], whh[col * H_ + k + 1]);
    }
    if (e < 64 * 512) {
        int i2 = e >> 9, h = e & 511;
        wih2[e] = packh2(wih[h * I_ + (i2 << 1)], wih[h * I_ + (i2 << 1) + 1]);
    }
    if (e < H_) biasv[e] = bih[e] + bhh[e];
}

// ---------------- xp = x @ W_ih^T + b_ih + b_hh, stored fp16 [B][T][H] --------
__global__ __launch_bounds__(512, 2) void xp_gemm(
    const float* __restrict__ x, const unsigned* __restrict__ wih2,
    const float* __restrict__ biasv, _Float16* __restrict__ xph) {
    __shared__ unsigned w2[64 * 512];   // 128 KB: half2 pairs over i
    __shared__ unsigned x2[32 * 64];    // 8 KB:  half2 pairs over i
    const int tid = threadIdx.x, b = blockIdx.x, t0 = blockIdx.y * 32;

    #pragma unroll
    for (int q = 0; q < 64; ++q) w2[tid + (q << 9)] = wih2[tid + (q << 9)];
    #pragma unroll
    for (int q = 0; q < 4; ++q) {
        int idx = tid * 4 + q;                  // 0..2047
        int t = idx >> 6, i2 = idx & 63;
        const float2 xv = *(const float2*)(x + ((size_t)b * T_ + t0 + t) * I_ + (i2 << 1));
        x2[idx] = packh2(xv.x, xv.y);
    }
    __syncthreads();
    const float bias = biasv[tid];
    for (int t = 0; t < 32; ++t) {
        float acc = bias;
        #pragma unroll
        for (int i2 = 0; i2 < 64; ++i2)
            acc = fdot2u(x2[(t << 6) + i2], w2[(i2 << 9) + tid], acc);
        xph[((size_t)b * T_ + t0 + t) * H_ + tid] = (_Float16)acc;
    }
}

// ---------------- serial recurrence: one WG per batch chain -------------------
// 512 threads: c=tid>>7 owns k-slice [c*128,c*128+128), g=tid&127 owns cols 4g..4g+3
// W_hh fp16: 96 k/slice in registers (192 VGPR), 32 k/slice in LDS (128 KB)
__global__ __launch_bounds__(512, 2) void rnn_fused(
    const unsigned* __restrict__ xp2,    // [B][T][256] half2 words
    const unsigned* __restrict__ wpack,
    const unsigned* __restrict__ wldsg,
    const float* __restrict__ fcw, const float* __restrict__ fcb,
    float* __restrict__ out) {
    __shared__ unsigned wlds[4 * 16 * 512];  // 128 KB
    __shared__ float part[4 * 512];          // 8 KB
    __shared__ unsigned h2buf[256];          // 1 KB: h as half2 pairs
    __shared__ float wsum[4];

    const int tid = threadIdx.x;
    const int b = blockIdx.x;
    const int c = tid >> 7, g = tid & 127;

    {   // one-time LDS weight load (coalesced uint4)
        const uint4* src = (const uint4*)wldsg;
        uint4* dst = (uint4*)wlds;
        #pragma unroll
        for (int q = 0; q < 16; ++q) dst[tid + (q << 9)] = src[tid + (q << 9)];
    }
    unsigned wreg[4][48];                    // 192 VGPRs of packed half2
    {
        const unsigned* wp = wpack + tid * 192;
        #pragma unroll
        for (int j = 0; j < 4; ++j)
            #pragma unroll
            for (int kk2 = 0; kk2 < 48; ++kk2)
                wreg[j][kk2] = wp[j * 48 + kk2];
    }
    if (tid < 256) h2buf[tid] = 0u;
    __syncthreads();

    const unsigned* xpb = xp2 + (size_t)b * T_ * 256;
    const uint4* wlds4 = (const uint4*)wlds;
    float4* part4 = (float4*)part;
    const float2* part2 = (const float2*)part;
    const int hb = c << 6;

    for (int t = 0; t < T_; ++t) {
        unsigned xpw = 0;                    // prefetch xp_t (hides L2 latency)
        if (tid < 256) xpw = xpb[t * 256 + tid];

        float a0 = 0.f, a1 = 0.f, a2 = 0.f, a3 = 0.f;
        #pragma unroll
        for (int kk2 = 0; kk2 < 48; ++kk2) {
            unsigned hh = h2buf[hb + kk2];   // wave-uniform broadcast
            a0 = fdot2u(wreg[0][kk2], hh, a0);
            a1 = fdot2u(wreg[1][kk2], hh, a1);
            a2 = fdot2u(wreg[2][kk2], hh, a2);
            a3 = fdot2u(wreg[3][kk2], hh, a3);
        }
        #pragma unroll
        for (int m = 0; m < 16; ++m) {
            unsigned hh = h2buf[hb + 48 + m];
            uint4 w4 = wlds4[((c << 4) + m) * 128 + g];  // 16B/lane coalesced
            a0 = fdot2u(w4.x, hh, a0);
            a1 = fdot2u(w4.y, hh, a1);
            a2 = fdot2u(w4.z, hh, a2);
            a3 = fdot2u(w4.w, hh, a3);
        }
        part4[(c << 7) + g] = make_float4(a0, a1, a2, a3);
        __syncthreads();

        if (tid < 256) {                     // reduce 4 chunks + tanh, repack h
            float2 s0 = part2[tid];
            float2 s1 = part2[256 + tid];
            float2 s2 = part2[512 + tid];
            float2 s3 = part2[768 + tid];
            U32H2 xu; xu.u = xpw;
            float pre0 = (float)xu.h.x + s0.x + s1.x + s2.x + s3.x;
            float pre1 = (float)xu.h.y + s0.y + s1.y + s2.y + s3.y;
            float e0 = __expf(2.0f * pre0), e1 = __expf(2.0f * pre1);
            float h0 = 1.0f - 2.0f / (e0 + 1.0f);
            float h1 = 1.0f - 2.0f / (e1 + 1.0f);
            h2buf[tid] = packh2(h0, h1);
        }
        __syncthreads();
    }

    // head: out[b] = dot(h, fc_w) + fc_b
    float p = 0.f;
    if (tid < 256) {
        U32H2 hu; hu.u = h2buf[tid];
        p = (float)hu.h.x * fcw[tid << 1] + (float)hu.h.y * fcw[(tid << 1) + 1];
    }
    #pragma unroll
    for (int off = 32; off >= 1; off >>= 1) p += __shfl_down(p, off, 64);
    if ((tid & 63) == 0 && tid < 256) wsum[tid >> 6] = p;
    __syncthreads();
    if (tid == 0) out[b] = wsum[0] + wsum[1] + wsum[2] + wsum[3] + fcb[0];
}

extern "C" void kernel_launch(void* const* d_in, const int* in_sizes, int n_in,
                              void* d_out, int out_size, void* d_ws, size_t ws_size,
                              hipStream_t stream) {
    const float* x   = (const float*)d_in[0];
    const float* wih = (const float*)d_in[1];
    const float* whh = (const float*)d_in[2];
    const float* bih = (const float*)d_in[3];
    const float* bhh = (const float*)d_in[4];
    const float* fcw = (const float*)d_in[5];
    const float* fcb = (const float*)d_in[6];
    float* out = (float*)d_out;

    // workspace layout (u32 units): xp2 | wpack | wldsg | wih2 | biasv  (~64.6 MiB)
    unsigned* xp2   = (unsigned*)d_ws;            // 64*1024*256 = 16,777,216
    unsigned* wpack = xp2 + 16777216;             // 98,304
    unsigned* wldsg = wpack + 98304;              // 32,768
    unsigned* wih2  = wldsg + 32768;              // 32,768
    float*    biasv = (float*)(wih2 + 32768);     // 512

    hipLaunchKernelGGL(prep, dim3(384), dim3(256), 0, stream,
                       wih, whh, bih, bhh, wpack, wldsg, wih2, biasv);
    hipLaunchKernelGGL(xp_gemm, dim3(B_, 32), dim3(512), 0, stream,
                       x, wih2, biasv, (_Float16*)xp2);
    hipLaunchKernelGGL(rnn_fused, dim3(B_), dim3(512), 0, stream,
                       xp2, wpack, wldsg, fcw, fcb, out);
}